// Round 12
// baseline (2175.152 us; speedup 1.0000x reference)
//
#include <hip/hip_runtime.h>

// ---------------- problem constants ----------------
#define T_STEPS 512
#define BATCH_N 256
#define IDIM    128
#define NDIM    1024
#define ODIM    10

// 128 WGs = 16 col-slices x 8 pairs. WG serves TWO independent batch-groups
// (gA=pair, gB=pair+8) with shared W/i2h registers. The two streams are
// interleaved so each stream's device-scope latency chain (publish-ack ->
// flag -> poll -> gather RT) hides under the other stream's compute.
// Counted vmcnt(4) at service start = gather done, publishes still in flight.
// bar2 = raw s_barrier (NOT __syncthreads: that would vmcnt(0)-drain the
// in-flight prefetched gather).
#define THREADS 256
#define GAIN 0.03125f

// ---------------- workspace layout (bytes) ----------------
#define YBUF_OFF    (33554432ull)                 // bf16 y [2][16][16][1024]
#define YBUF_HALF   (524288ull)
#define YHALF_EL    (262144u)
#define FLG_OFF     (YBUF_OFF + 2*YBUF_HALF)
#define FLG_BYTES   (8192ull)                     // [16][64] flags (4KB) + 4KB dummy pad
#define XT_OFF      (FLG_OFF + FLG_BYTES)
#define XT_BYTES    (1048576ull)
#define WS_NEED     (XT_OFF + XT_BYTES)

typedef short    s16x8 __attribute__((ext_vector_type(8)));
typedef float    f32x4 __attribute__((ext_vector_type(4)));
typedef unsigned u32x4 __attribute__((ext_vector_type(4)));

__device__ __forceinline__ unsigned short f2bf(float f) {
  unsigned u = __builtin_bit_cast(unsigned, f);
  u += 0x7fffu + ((u >> 16) & 1u);               // RTNE
  return (unsigned short)(u >> 16);
}

// ---------------- batch fp32 -> bf16 prepass ----------------
__global__ void horn_convert(const float* __restrict__ src, unsigned short* __restrict__ dst) {
  size_t gid = (size_t)blockIdx.x * 256 + threadIdx.x;
  const f32x4* s4 = reinterpret_cast<const f32x4*>(src) + gid * 2;
  f32x4 a = s4[0], b = s4[1];
  u32x4 o;
  o[0] = (unsigned)f2bf(a[0]) | ((unsigned)f2bf(a[1]) << 16);
  o[1] = (unsigned)f2bf(a[2]) | ((unsigned)f2bf(a[3]) << 16);
  o[2] = (unsigned)f2bf(b[0]) | ((unsigned)f2bf(b[1]) << 16);
  o[3] = (unsigned)f2bf(b[2]) | ((unsigned)f2bf(b[3]) << 16);
  reinterpret_cast<u32x4*>(dst)[gid] = o;
}

// ---------------- persistent recurrent kernel ----------------
__launch_bounds__(THREADS, 1)
__global__ void horn_persistent(const unsigned short* __restrict__ batchbf,
                                const float* __restrict__ i2h_w,
                                const float* __restrict__ i2h_b,
                                const float* __restrict__ h2h_w,
                                const float* __restrict__ h2h_b,
                                unsigned short* ybuf,     // bf16 [2][16][16][1024]
                                unsigned int*  flags,     // u32 [16][64] + pad
                                float* xT)                // [256][1024] fp32
{
  __shared__ char  ylds[32768];
  __shared__ f32x4 red[4][4][64];
  __shared__ char  batchL[2][4096];

  const int tid  = threadIdx.x;
  const int lane = tid & 63;
  const int wv   = tid >> 6;          // wave 0..3: K-quarter wv, owned ct = wv
  const int pr   = blockIdx.x & 7;    // pair
  const int s    = blockIdx.x >> 3;   // col-slice 0..15 (64 cols)
  const int l15  = lane & 15;
  const int kb   = lane >> 4;
  const int jc   = s * 64 + wv * 16 + l15;       // owned output column
  const int gidx[2] = {pr, pr + 8};              // stream -> batch group

  // ---- W fragments: 4 ct x 8 kc (K-quarter wv), xGAIN = 128 VGPRs ----
  s16x8 wfrag[4][8];
  #pragma unroll
  for (int ct = 0; ct < 4; ++ct) {
    #pragma unroll
    for (int kc = 0; kc < 8; ++kc) {
      const float* gp = h2h_w + (size_t)(s * 64 + ct * 16 + l15) * NDIM
                        + wv * 256 + kc * 32 + kb * 8;
      f32x4 a = *reinterpret_cast<const f32x4*>(gp);
      f32x4 b = *reinterpret_cast<const f32x4*>(gp + 4);
      s16x8 v;
      v[0] = (short)f2bf(a[0]*GAIN); v[1] = (short)f2bf(a[1]*GAIN);
      v[2] = (short)f2bf(a[2]*GAIN); v[3] = (short)f2bf(a[3]*GAIN);
      v[4] = (short)f2bf(b[0]*GAIN); v[5] = (short)f2bf(b[1]*GAIN);
      v[6] = (short)f2bf(b[2]*GAIN); v[7] = (short)f2bf(b[3]*GAIN);
      wfrag[ct][kc] = v;
    }
  }
  s16x8 i2hf[4];
  #pragma unroll
  for (int kc = 0; kc < 4; ++kc) {
    const float* gp = i2h_w + (size_t)jc * IDIM + kc * 32 + kb * 8;
    s16x8 v;
    #pragma unroll
    for (int e = 0; e < 8; ++e) v[e] = (short)f2bf(gp[e]);
    i2hf[kc] = v;
  }
  const float bias = i2h_b[jc] + GAIN * h2h_b[jc];

  // ---- per-stream pointers ----
  const char* gb[2];
  unsigned short* pub0[2];
  const unsigned* flp[2];
  unsigned* fs[2];
  #pragma unroll
  for (int X = 0; X < 2; ++X) {
    int g = gidx[X];
    gb[X]   = (const char*)ybuf + (size_t)g * 32768 + (size_t)tid * 16;
    pub0[X] = ybuf + (size_t)(g * 16 + kb * 4) * 1024 + jc;
    flp[X]  = flags + g * 64 + lane;
    fs[X]   = flags + g * 64 + s * 4 + wv;
  }
  unsigned* dmy = flags + 1024 + blockIdx.x * 8 + wv;   // dummy pad
  const char* bbase = (const char*)batchbf;
  const int batch_lane = tid * 16;                      // linear global chunk
  const int brow = tid >> 4, bcp = tid & 15;
  const int bldsoff = brow * 256 + ((bcp ^ (brow & 7)) << 4); // swizzled LDS dest

  float xs[2][4] = {{0,0,0,0},{0,0,0,0}};
  float ys[2][4] = {{0,0,0,0},{0,0,0,0}};

  u32x4 vy0, vy1, vy2, vy3, vy4, vy5, vy6, vy7, vbat;

  // issue bundle: 8 coalesced y loads (sc0 sc1) + 1 batch load (plain) = 9 vmem
  #define GBUNDLE(YB, BP)                                                   \
    { const char* y_ = (YB);                                                \
      asm volatile(                                                         \
        "global_load_dwordx4 %0, %9, off sc0 sc1\n\t"                       \
        "global_load_dwordx4 %1, %10, off sc0 sc1\n\t"                      \
        "global_load_dwordx4 %2, %11, off sc0 sc1\n\t"                      \
        "global_load_dwordx4 %3, %12, off sc0 sc1\n\t"                      \
        "global_load_dwordx4 %4, %13, off sc0 sc1\n\t"                      \
        "global_load_dwordx4 %5, %14, off sc0 sc1\n\t"                      \
        "global_load_dwordx4 %6, %15, off sc0 sc1\n\t"                      \
        "global_load_dwordx4 %7, %16, off sc0 sc1\n\t"                      \
        "global_load_dwordx4 %8, %17, off"                                  \
        : "=&v"(vy0), "=&v"(vy1), "=&v"(vy2), "=&v"(vy3),                   \
          "=&v"(vy4), "=&v"(vy5), "=&v"(vy6), "=&v"(vy7), "=&v"(vbat)       \
        : "v"(y_), "v"(y_+4096), "v"(y_+8192), "v"(y_+12288),               \
          "v"(y_+16384), "v"(y_+20480), "v"(y_+24576), "v"(y_+28672),       \
          "v"(BP)                                                           \
        : "memory"); }

  #define STG(r, vr) { int B_ = (r) * 4096 + tid * 16; int row_ = B_ >> 11; \
    *reinterpret_cast<u32x4*>(ylds + (B_ ^ ((row_ & 7) << 4))) = vr; }

  #define UPD(X, r, yw) { float z_ = z[r];                                  \
    float e_ = __expf(z_ + z_);                                             \
    float th_ = fmaf(-2.0f, __builtin_amdgcn_rcpf(e_ + 1.0f), 1.0f);        \
    float yn_ = ys[X][r] + 0.1f*(th_ - xs[X][r] - 0.2f*ys[X][r]);           \
    xs[X][r] += 0.1f*yn_; ys[X][r] = yn_; yw = f2bf(yn_); }

  // X = stream staged/computed; OX = other stream (flag store, spin+issue)
  // TFLAG: value stored to fs[OX]; TSPIN: spin target on flp[OX];
  // TISS: step issued for stream OX; DOISS: do spin+issue at all.
  #define SERVICE(X, OX, TFLAG, TSPIN, TISS, DOISS, PN)                     \
  {                                                                         \
    asm volatile("s_waitcnt vmcnt(4)" ::: "memory");                        \
    __builtin_amdgcn_sched_barrier(0);                                      \
    STG(0, vy0) STG(1, vy1) STG(2, vy2) STG(3, vy3)                         \
    STG(4, vy4) STG(5, vy5) STG(6, vy6) STG(7, vy7)                         \
    *reinterpret_cast<u32x4*>(&batchL[X][bldsoff]) = vbat;                  \
    asm volatile("s_waitcnt vmcnt(0)" ::: "memory");                        \
    __builtin_amdgcn_sched_barrier(0);                                      \
    __syncthreads();                      /* bar1: tile+batch visible */    \
    if (lane == 0) {                                                        \
      unsigned fv_ = (unsigned)(TFLAG);                                     \
      asm volatile("global_store_dword %0, %1, off sc0 sc1"                 \
                   :: "v"(fs[OX]), "v"(fv_) : "memory");                    \
    }                                                                       \
    f32x4 uacc = {bias, bias, bias, bias};                                  \
    _Pragma("unroll")                                                       \
    for (int kc = 0; kc < 4; ++kc) {                                        \
      s16x8 a_ = *reinterpret_cast<const s16x8*>(                           \
          &batchL[X][l15 * 256 + (((kc * 4 + kb) ^ (l15 & 7)) << 4)]);      \
      uacc = __builtin_amdgcn_mfma_f32_16x16x32_bf16(a_, i2hf[kc], uacc, 0, 0, 0); \
    }                                                                       \
    f32x4 c0 = {0,0,0,0}, c1 = {0,0,0,0}, c2 = {0,0,0,0}, c3 = {0,0,0,0};   \
    _Pragma("unroll")                                                       \
    for (int kc = 0; kc < 8; ++kc) {                                        \
      int boff = (l15 * 2048 + wv * 512 + kc * 64 + kb * 16) ^ ((l15 & 7) << 4); \
      s16x8 a_ = *reinterpret_cast<const s16x8*>(ylds + boff);              \
      c0 = __builtin_amdgcn_mfma_f32_16x16x32_bf16(a_, wfrag[0][kc], c0, 0, 0, 0); \
      c1 = __builtin_amdgcn_mfma_f32_16x16x32_bf16(a_, wfrag[1][kc], c1, 0, 0, 0); \
      c2 = __builtin_amdgcn_mfma_f32_16x16x32_bf16(a_, wfrag[2][kc], c2, 0, 0, 0); \
      c3 = __builtin_amdgcn_mfma_f32_16x16x32_bf16(a_, wfrag[3][kc], c3, 0, 0, 0); \
    }                                                                       \
    red[wv][0][lane] = c0; red[wv][1][lane] = c1;                           \
    red[wv][2][lane] = c2; red[wv][3][lane] = c3;                           \
    if (DOISS) {                                                            \
      while (true) { unsigned pv_;                                          \
        asm volatile("global_load_dword %0, %1, off sc0 sc1\n\t"            \
                     "s_waitcnt vmcnt(0)"                                   \
                     : "=v"(pv_) : "v"(flp[OX]) : "memory");                \
        if (__all((int)pv_ >= (TSPIN))) break;                              \
        __builtin_amdgcn_s_sleep(1);                                        \
      }                                                                     \
      const char* ya_ = gb[OX] + (size_t)((TISS) & 1) * YBUF_HALF;          \
      const char* ba_ = bbase + ((size_t)(TISS) * 256 + gidx[OX] * 16) * 256 + batch_lane; \
      GBUNDLE(ya_, ba_)                                                     \
    }                                                                       \
    asm volatile("s_waitcnt lgkmcnt(0)" ::: "memory");                      \
    __builtin_amdgcn_sched_barrier(0);                                      \
    __builtin_amdgcn_s_barrier();         /* bar2: raw, vmcnt preserved */  \
    __builtin_amdgcn_sched_barrier(0);                                      \
    f32x4 z = uacc;                                                         \
    z += red[0][wv][lane]; z += red[1][wv][lane];                           \
    z += red[2][wv][lane]; z += red[3][wv][lane];                           \
    unsigned yw0, yw1, yw2, yw3;                                            \
    UPD(X, 0, yw0) UPD(X, 1, yw1) UPD(X, 2, yw2) UPD(X, 3, yw3)             \
    { unsigned short* b0 = pub0[X] + (size_t)(PN) * YHALF_EL;               \
      unsigned short* b1 = b0 + 2 * NDIM;                                   \
      asm volatile(                                                         \
        "global_store_short %4, %0, off offset:0    sc0 sc1\n\t"            \
        "global_store_short %4, %1, off offset:2048 sc0 sc1\n\t"            \
        "global_store_short %5, %2, off offset:0    sc0 sc1\n\t"            \
        "global_store_short %5, %3, off offset:2048 sc0 sc1"                \
        :: "v"(yw0), "v"(yw1), "v"(yw2), "v"(yw3), "v"(b0), "v"(b1)         \
        : "memory"); }                                                      \
  }

  // ---- prologue: drain weight loads, issue gatherA(0)+batchA(0)+4 dummies ----
  asm volatile("s_waitcnt vmcnt(0)" ::: "memory");
  {
    const char* ya_ = gb[0];                                   // parity 0
    const char* ba_ = bbase + ((size_t)gidx[0] * 16) * 256 + batch_lane;
    GBUNDLE(ya_, ba_)
    unsigned z0 = 0u;
    asm volatile(
      "global_store_dword %0, %1, off sc0 sc1\n\t"
      "global_store_dword %0, %1, off sc0 sc1\n\t"
      "global_store_dword %0, %1, off sc0 sc1\n\t"
      "global_store_dword %0, %1, off sc0 sc1"
      :: "v"(dmy), "v"(z0) : "memory");
  }

  #pragma unroll 1
  for (int t = 0; t < T_STEPS; ++t) {
    const int p = t & 1, pn = p ^ 1;
    // A-service: compute stream 0 step t; flagB=t; spin fB>=t; issue B(t)
    SERVICE(0, 1, t, t, t, 1, pn)
    // B-service: compute stream 1 step t; flagA=t+1; spin fA>=t+1; issue A(t+1)
    SERVICE(1, 0, t + 1, t + 1, t + 1, (t < T_STEPS - 1), pn)
  }
  #undef SERVICE
  #undef GBUNDLE
  #undef STG
  #undef UPD

  asm volatile("s_waitcnt vmcnt(0)" ::: "memory");

  // ---- write x_T for both streams ----
  #pragma unroll
  for (int q = 0; q < 4; ++q) {
    int rowA = gidx[0] * 16 + kb * 4 + q;
    int rowB = gidx[1] * 16 + kb * 4 + q;
    xT[(size_t)rowA * NDIM + jc] = xs[0][q];
    xT[(size_t)rowB * NDIM + jc] = xs[1][q];
  }
}

// ---------------- final readout: out = x_T @ h2o^T + b ----------------
__global__ void horn_out(const float* __restrict__ xT, const float* __restrict__ h2o_w,
                         const float* __restrict__ h2o_b, float* __restrict__ out) {
  int b = blockIdx.x;
  int lane = threadIdx.x;                  // 64 threads
  float p[ODIM];
  #pragma unroll
  for (int o = 0; o < ODIM; ++o) p[o] = 0.f;
  for (int it = 0; it < NDIM / 64; ++it) {
    int n = it * 64 + lane;
    float xv = xT[(size_t)b * NDIM + n];
    #pragma unroll
    for (int o = 0; o < ODIM; ++o) p[o] += xv * h2o_w[o * NDIM + n];
  }
  #pragma unroll
  for (int o = 0; o < ODIM; ++o) {
    float v = p[o];
    #pragma unroll
    for (int off = 32; off >= 1; off >>= 1) v += __shfl_down(v, off, 64);
    if (lane == 0) out[b * ODIM + o] = v + h2o_b[o];
  }
}

__global__ void horn_fail(float* out) {    // loud sentinel if ws too small
  int i = blockIdx.x * 256 + threadIdx.x;
  if (i < BATCH_N * ODIM) out[i] = 12345.0f;
}

extern "C" void kernel_launch(void* const* d_in, const int* in_sizes, int n_in,
                              void* d_out, int out_size, void* d_ws, size_t ws_size,
                              hipStream_t stream) {
  const float* batch = (const float*)d_in[0];
  const float* i2h_w = (const float*)d_in[1];
  const float* i2h_b = (const float*)d_in[2];
  const float* h2h_w = (const float*)d_in[3];
  const float* h2h_b = (const float*)d_in[4];
  const float* h2o_w = (const float*)d_in[5];
  const float* h2o_b = (const float*)d_in[6];
  float* out = (float*)d_out;
  char* ws = (char*)d_ws;

  if (ws_size < WS_NEED) {
    horn_fail<<<16, 256, 0, stream>>>(out);
    return;
  }

  hipMemsetAsync(ws + YBUF_OFF, 0, YBUF_HALF, stream);   // y_0 = 0 (parity 0)
  hipMemsetAsync(ws + FLG_OFF, 0, FLG_BYTES, stream);    // flags + pad = 0

  horn_convert<<<8192, 256, 0, stream>>>(batch, (unsigned short*)(ws + 0));

  horn_persistent<<<128, THREADS, 0, stream>>>(
      (const unsigned short*)(ws + 0), i2h_w, i2h_b, h2h_w, h2h_b,
      (unsigned short*)(ws + YBUF_OFF), (unsigned int*)(ws + FLG_OFF),
      (float*)(ws + XT_OFF));

  horn_out<<<BATCH_N, 64, 0, stream>>>((const float*)(ws + XT_OFF), h2o_w, h2o_b, out);
}